// Round 1
// baseline (304.253 us; speedup 1.0000x reference)
//
#include <hip/hip_runtime.h>
#include <math.h>

// ---------- types ----------
typedef __attribute__((ext_vector_type(8)))  short  short8;   // 8 bf16 (4 VGPRs) MFMA A/B frag
typedef __attribute__((ext_vector_type(16))) float  f32x16;   // 32x32 MFMA C/D frag
typedef __attribute__((ext_vector_type(4)))  float  float4v;
typedef __attribute__((ext_vector_type(8)))  unsigned short ushort8;
typedef __attribute__((ext_vector_type(4)))  unsigned short ushort4v;

#define NDIM 4096
#define BM 256
#define BN 128
#define BK 64

#define NA_BLOCKS 2048   // A-convert grid-stride blocks
#define NW_BLOCKS 4096   // W-transpose blocks (64x64 tiles over 4096^2)

// fp32 -> bf16, round-to-nearest-even
__device__ __forceinline__ unsigned short f2bf(float f) {
  unsigned u = __builtin_bit_cast(unsigned, f);
  u += 0x7fffu + ((u >> 16) & 1u);
  return (unsigned short)(u >> 16);
}

// async global->LDS DMA, 16B/lane. LDS dest must be wave-uniform base + lane*16.
__device__ __forceinline__ void gload_lds16(const unsigned short* g, unsigned short* l) {
  __builtin_amdgcn_global_load_lds(
      (const __attribute__((address_space(1))) void*)g,
      (__attribute__((address_space(3))) void*)l, 16, 0, 0);
}

// ---------- fused prep, rewritten for memory-roofline ----------
// A-part (blocks 0..NA_BLOCKS-1): grid-stride fp32->bf16 stream.
//   Every instruction is wave-contiguous: float4 loads (1KB/wave/instr),
//   ushort4 stores (512B/wave/instr). 8 independent loads in flight/thread.
// W-part (blocks NA_BLOCKS..): 64x64 tile transpose+convert.
//   4x4 in-REGISTER transpose (replaces 16 bank-conflicted scalar ds_read_u16),
//   LDS [64][72] (row 144B = 36 banks -> 4-bank rotation, 16B-aligned rows),
//   phase-2 ushort8 vector reads + coalesced 128B-per-row global stores.
__global__ __launch_bounds__(256)
void prep(const float* __restrict__ A, unsigned short* __restrict__ Abf,
          const float* __restrict__ W, unsigned short* __restrict__ Wt) {
  __shared__ unsigned short tile[64][72];   // [n_local][k_local], 9216 B
  const int t = threadIdx.x;                // 0..255
  if (blockIdx.x < NA_BLOCKS) {
    // 2048 blocks * 256 thr * 8 iters = 4,194,304 float4 = 4096^2 floats exactly
    const int base   = blockIdx.x * 256 + t;
    const int stride = NA_BLOCKS * 256;
#pragma unroll
    for (int it = 0; it < 8; ++it) {
      const size_t idx = (size_t)(base + it * stride) * 4;   // float index
      float4v v = *(const float4v*)(A + idx);
      ushort4v o;
      o[0] = f2bf(v[0]); o[1] = f2bf(v[1]); o[2] = f2bf(v[2]); o[3] = f2bf(v[3]);
      *(ushort4v*)(Abf + idx) = o;
    }
  } else {
    const int b  = blockIdx.x - NA_BLOCKS;          // 0..4095
    const int n0 = (b & 63) * 64;
    const int k0 = (b >> 6) * 64;
    // phase 1: thread owns the 4x4 block at k = kq*4..+3, n = nc..+3
    const int kq = t >> 4;                          // 0..15
    const int nc = (t & 15) * 4;
    float4v v[4];
#pragma unroll
    for (int r = 0; r < 4; ++r)                     // 16 lanes x 16B = 256B/row, coalesced
      v[r] = *(const float4v*)&W[(size_t)(k0 + kq * 4 + r) * NDIM + n0 + nc];
#pragma unroll
    for (int c = 0; c < 4; ++c) {                   // register transpose + convert
      ushort4v u;
#pragma unroll
      for (int r = 0; r < 4; ++r) u[r] = f2bf(v[r][c]);
      *(ushort4v*)&tile[nc + c][kq * 4] = u;        // 8B vector LDS store
    }
    __syncthreads();
    // phase 2: row n = t>>2 (4 threads/row), 2 x ushort8 each = 128B/row
    const int n  = t >> 2;
    const int cb = (t & 3) * 16;                    // ushort col base
    unsigned short* dst = Wt + (size_t)(n0 + n) * NDIM + k0 + cb;
#pragma unroll
    for (int h = 0; h < 2; ++h) {
      ushort8 w8 = *(const ushort8*)&tile[n][cb + h * 8];   // 16B-aligned (row=144B)
      *(ushort8*)(dst + h * 8) = w8;
    }
  }
}

// ---------- gemm: 256x128 block, wave tile 128x64, MFMA 32x32x16, XOR-8 swizzle ----------
// (UNCHANGED from verified 148.6us version — baseline for clean attribution.)
// LDS-BW-bound analysis (R4 post-mortem): wave tile 128x64 raises FLOP/LDS-byte
// 32 -> 42.7; XOR-8 swizzle (chunk c of row r stored at c^(r&7)) makes every
// 8-consecutive-lane group of a b128 read cover all 32 banks -> conflict-free.
// Swizzle applied on DMA SOURCE address (dest must stay lane-linear), undone at
// fragment read. A-frag: A[m=lane&31][k=(lane>>5)*8+j]; C/D: col=lane&31,
// row=(reg&3)+8*(reg>>2)+4*(lane>>5) [m74/m101].
__global__ __launch_bounds__(256, 2)
void gemm_bt_quant(const unsigned short* __restrict__ A,
                   const unsigned short* __restrict__ Bt,
                   const float* __restrict__ bias,
                   float* __restrict__ C) {
  __shared__ unsigned short As[BM * BK];   // 32 KB
  __shared__ unsigned short Bs[BN * BK];   // 16 KB

  const int tid  = threadIdx.x;
  const int lane = tid & 63;
  const int wid  = tid >> 6;               // 4 waves, 2x2: wm in {0,128}, wn in {0,64}
  const int wm   = (wid >> 1) * 128;
  const int wn   = (wid & 1) * 64;
  const int m0   = blockIdx.y * BM;
  const int n0   = blockIdx.x * BN;

  // staging: slot s = p*256+tid -> dest row s>>3, dest chunk s&7;
  // source logical chunk = (s&7) ^ (row&7). Rows advance 32/pass (mult of 8),
  // so row&7 == (tid>>3)&7 for all passes.
  const int srow = tid >> 3;                     // 0..31
  const int sc   = (tid & 7) ^ (srow & 7);       // swizzled source chunk
  const unsigned short* Ag = A  + (size_t)(m0 + srow) * NDIM + sc * 8;
  const unsigned short* Bg = Bt + (size_t)(n0 + srow) * NDIM + sc * 8;

  const int fr = lane & 31;                // fragment row within 32-tile
  const int fh = lane >> 5;                // K-half selector
  const int fsw = fr & 7;                  // read-side swizzle (row&7)

  f32x16 acc[4][2] = {};

  for (int kt = 0; kt < NDIM; kt += BK) {
#pragma unroll
    for (int p = 0; p < 8; ++p)
      gload_lds16(Ag + kt + (size_t)(p * 32) * NDIM, &As[(p * 256 + tid) * 8]);
#pragma unroll
    for (int p = 0; p < 4; ++p)
      gload_lds16(Bg + kt + (size_t)(p * 32) * NDIM, &Bs[(p * 256 + tid) * 8]);
    __syncthreads();

#pragma unroll
    for (int h = 0; h < 4; ++h) {          // K16 steps within BK
      const int cph = (2 * h + fh) ^ fsw;  // physical chunk for this lane
      short8 af[4], bfr[2];
#pragma unroll
      for (int i = 0; i < 4; ++i)
        af[i] = *(const short8*)&As[(wm + i * 32 + fr) * BK + cph * 8];
#pragma unroll
      for (int j = 0; j < 2; ++j)
        bfr[j] = *(const short8*)&Bs[(wn + j * 32 + fr) * BK + cph * 8];
#pragma unroll
      for (int i = 0; i < 4; ++i)
#pragma unroll
        for (int j = 0; j < 2; ++j)
          acc[i][j] = __builtin_amdgcn_mfma_f32_32x32x16_bf16(af[i], bfr[j], acc[i][j], 0, 0, 0);
    }
    __syncthreads();
  }

  // epilogue: fused quant + bias
  const float inv = 1.0f / 256.0f;
#pragma unroll
  for (int j = 0; j < 2; ++j) {
    const int col = n0 + wn + j * 32 + fr;
    const float qb = rintf(bias[col] * 256.0f) * inv;
#pragma unroll
    for (int i = 0; i < 4; ++i) {
      const int rb = m0 + wm + i * 32 + 4 * fh;
#pragma unroll
      for (int r = 0; r < 16; ++r) {
        const int row = rb + (r & 3) + 8 * (r >> 2);
        C[(size_t)row * NDIM + col] = rintf(acc[i][j][r] * 256.0f) * inv + qb;
      }
    }
  }
}

// ---------- fallback (ws too small): fp32 tiled GEMM, exact ----------
__global__ void gemm_fb(const float* __restrict__ A, const float* __restrict__ W,
                        const float* __restrict__ bias, float* __restrict__ C) {
  __shared__ float As[32][33], Ws[32][33];
  int tx = threadIdx.x, ty = threadIdx.y;     // (32,8)
  int m0 = blockIdx.y * 32, n0 = blockIdx.x * 32;
  float acc[4] = {0.f, 0.f, 0.f, 0.f};
  for (int k0 = 0; k0 < NDIM; k0 += 32) {
#pragma unroll
    for (int i = 0; i < 4; ++i) {
      int r = ty + i * 8;
      As[r][tx] = A[(size_t)(m0 + r) * NDIM + k0 + tx];
      Ws[r][tx] = W[(size_t)(k0 + r) * NDIM + n0 + tx];
    }
    __syncthreads();
#pragma unroll
    for (int k = 0; k < 32; ++k) {
      float wv = Ws[k][tx];
#pragma unroll
      for (int i = 0; i < 4; ++i) acc[i] += As[ty + i * 8][k] * wv;
    }
    __syncthreads();
  }
  float qb = rintf(bias[n0 + tx] * 256.0f) * (1.0f / 256.0f);
#pragma unroll
  for (int i = 0; i < 4; ++i)
    C[(size_t)(m0 + ty + i * 8) * NDIM + n0 + tx] =
        rintf(acc[i] * 256.0f) * (1.0f / 256.0f) + qb;
}

extern "C" void kernel_launch(void* const* d_in, const int* in_sizes, int n_in,
                              void* d_out, int out_size, void* d_ws, size_t ws_size,
                              hipStream_t stream) {
  const float* A    = (const float*)d_in[0];
  const float* W    = (const float*)d_in[1];
  const float* bias = (const float*)d_in[2];
  float* C = (float*)d_out;
  const size_t nElem = (size_t)NDIM * NDIM;

  if (ws_size >= nElem * 4) {   // need 2 bf16 matrices = 64 MB
    unsigned short* Abf = (unsigned short*)d_ws;
    unsigned short* Wt  = Abf + nElem;
    prep<<<NA_BLOCKS + NW_BLOCKS, 256, 0, stream>>>(A, Abf, W, Wt);
    gemm_bt_quant<<<dim3(NDIM / BN, NDIM / BM), 256, 0, stream>>>(Abf, Wt, bias, C);
  } else {
    gemm_fb<<<dim3(128, 128), dim3(32, 8), 0, stream>>>(A, W, bias, C);
  }
}